// Round 1
// baseline (7586.950 us; speedup 1.0000x reference)
//
#include <hip/hip_runtime.h>
#include <math.h>

// ---------------- constants ----------------
constexpr float RADIUS     = 0.1125f;          // 1.5*6*0.025*0.5
constexpr float INV_RADIUS = 1.0f / RADIUS;
constexpr float DT         = 1.0f / 50.0f;
constexpr float FOPI       = 1.2732395447351628f; // 4/pi

struct Geom { float fx, fy, fz, win; int base; }; // 20 B, trilinear fracs + window + base bin

// ---------------- prep: pos2, feats=[1,vel2] ----------------
__global__ __launch_bounds__(256) void k_prep(const float* __restrict__ pos,
                                              const float* __restrict__ vel,
                                              float* __restrict__ pos2,
                                              float* __restrict__ feats, int n) {
  int i = blockIdx.x * blockDim.x + threadIdx.x;
  if (i >= n) return;
  float vx = vel[i*3+0], vy = vel[i*3+1], vz = vel[i*3+2];
  float v2x = vx, v2y = vy + DT * (-9.81f), v2z = vz;
  pos2[i*3+0] = pos[i*3+0] + DT * 0.5f * (v2x + vx);
  pos2[i*3+1] = pos[i*3+1] + DT * 0.5f * (v2y + vy);
  pos2[i*3+2] = pos[i*3+2] + DT * 0.5f * (v2z + vz);
  feats[i*4+0] = 1.0f;
  feats[i*4+1] = v2x; feats[i*4+2] = v2y; feats[i*4+3] = v2z;
}

// ---------------- rowptr: lower_bound over sorted dst arrays ----------------
__global__ __launch_bounds__(256) void k_rowptr(const int* __restrict__ ffdst, int Eff,
                                                const int* __restrict__ bfdst, int Ebf,
                                                int* __restrict__ rowff, int* __restrict__ rowbf,
                                                int n) {
  int d = blockIdx.x * blockDim.x + threadIdx.x;
  if (d > n) return;
  { int lo = 0, hi = Eff;
    while (lo < hi) { int mid = (lo + hi) >> 1; if (ffdst[mid] < d) lo = mid + 1; else hi = mid; }
    rowff[d] = lo; }
  { int lo = 0, hi = Ebf;
    while (lo < hi) { int mid = (lo + hi) >> 1; if (bfdst[mid] < d) lo = mid + 1; else hi = mid; }
    rowbf[d] = lo; }
}

// ---------------- per-edge geometry (ball_to_cube etc.) ----------------
__global__ __launch_bounds__(256) void k_geom(const int* __restrict__ srcs,
                                              const int* __restrict__ dsts,
                                              const float* __restrict__ srcpos,
                                              const float* __restrict__ dstpos,
                                              Geom* __restrict__ geo, int E) {
  int e = blockIdx.x * blockDim.x + threadIdx.x;
  if (e >= E) return;
  int s = srcs[e], d = dsts[e];
  float rx = (srcpos[s*3+0] - dstpos[d*3+0]) * INV_RADIUS;
  float ry = (srcpos[s*3+1] - dstpos[d*3+1]) * INV_RADIUS;
  float rz = (srcpos[s*3+2] - dstpos[d*3+2]) * INV_RADIUS;
  float r2 = rx*rx + ry*ry + rz*rz;
  float t = 1.0f - r2;
  float win = t * t * t;
  win = fminf(fmaxf(win, 0.0f), 1.0f);
  // ball -> cube (volume preserving), exact reference arithmetic
  float x = rx, y = ry, z = rz;
  float sq = r2;
  float norm = sqrtf(sq + 1e-24f);
  float xy_sq = x*x + y*y;
  bool zero = sq < 1e-12f;
  bool cone = 1.25f * z * z > xy_sq;
  float s_cone = sqrtf(3.0f * norm / (norm + fabsf(z) + 1e-12f));
  float s_side = norm / sqrtf(xy_sq + 1e-24f);
  float sgnz = (z > 0.0f) ? 1.0f : ((z < 0.0f) ? -1.0f : 0.0f);
  float xc = zero ? 0.0f : (cone ? x * s_cone : x * s_side);
  float yc = zero ? 0.0f : (cone ? y * s_cone : y * s_side);
  float zc = zero ? 0.0f : (cone ? sgnz * norm : 1.5f * z);
  float nxy_sq = xc*xc + yc*yc;
  float nxy = sqrtf(nxy_sq + 1e-24f);
  bool zero_xy = nxy_sq < 1e-12f;
  bool xbig = fabsf(xc) > fabsf(yc);
  float dx_ = (fabsf(xc) > 1e-12f) ? xc : 1.0f;
  float dy_ = (fabsf(yc) > 1e-12f) ? yc : 1.0f;
  float sgnx = (xc > 0.0f) ? 1.0f : ((xc < 0.0f) ? -1.0f : 0.0f);
  float sgny = (yc > 0.0f) ? 1.0f : ((yc < 0.0f) ? -1.0f : 0.0f);
  float tx = sgnx * nxy, ty = sgny * nxy;
  float xq = zero_xy ? 0.0f : (xbig ? tx : ty * FOPI * atanf(xc / dy_));
  float yq = zero_xy ? 0.0f : (xbig ? tx * FOPI * atanf(yc / dx_) : ty);
  // grid coords
  float gx = (xq + 1.0f) * 1.5f;
  float gy = (yq + 1.0f) * 1.5f;
  float gz = (zc + 1.0f) * 1.5f;
  float g0x = fminf(fmaxf(floorf(gx), 0.0f), 2.0f);
  float g0y = fminf(fmaxf(floorf(gy), 0.0f), 2.0f);
  float g0z = fminf(fmaxf(floorf(gz), 0.0f), 2.0f);
  Geom g;
  g.fx = gx - g0x; g.fy = gy - g0y; g.fz = gz - g0z; g.win = win;
  g.base = (int)g0z * 16 + (int)g0y * 4 + (int)g0x;
  geo[e] = g;
}

// ---------------- layer0: c0o | c0f | d0 -> relu -> x0[n][96] ----------------
__global__ __launch_bounds__(256) void k_layer0(const float* __restrict__ feats,
                                                const float* __restrict__ bfeats,
                                                const int* __restrict__ ffsrc,
                                                const int* __restrict__ rowff,
                                                const Geom* __restrict__ gff,
                                                const int* __restrict__ bfsrc,
                                                const int* __restrict__ rowbf,
                                                const Geom* __restrict__ gbf,
                                                const float* __restrict__ W0f, const float* __restrict__ b0f,
                                                const float* __restrict__ W0o, const float* __restrict__ b0o,
                                                const float* __restrict__ Wd0, const float* __restrict__ bd0,
                                                float* __restrict__ x0, int n) {
  __shared__ float Tf[4][64*4];
  __shared__ float To[4][64*3];
  __shared__ float fd[4][4];
  int tid = threadIdx.x, lane = tid & 63, g = tid >> 6;
  int dst = blockIdx.x * 4 + g;
  bool valid = dst < n;
  for (int idx = lane; idx < 64*4; idx += 64) Tf[g][idx] = 0.0f;
  for (int idx = lane; idx < 64*3; idx += 64) To[g][idx] = 0.0f;
  if (lane < 4) fd[g][lane] = valid ? feats[dst*4 + lane] : 0.0f;
  __syncthreads();
  // ff scatter (Cin=4): lanes 0..31 -> corner c=lane>>2, channel i=lane&3
  int e0 = valid ? rowff[dst] : 0, e1 = valid ? rowff[dst+1] : 0;
  for (int e = e0; e < e1; ++e) {
    Geom gm = gff[e];
    int src = ffsrc[e];
    if (lane < 32) {
      int c = lane >> 2, i = lane & 3;
      int dx = c & 1, dy = (c >> 1) & 1, dz = c >> 2;
      float w = gm.win * (dx ? gm.fx : 1.0f - gm.fx)
                       * (dy ? gm.fy : 1.0f - gm.fy)
                       * (dz ? gm.fz : 1.0f - gm.fz);
      int bin = gm.base + dz*16 + dy*4 + dx;
      Tf[g][bin*4 + i] += w * feats[src*4 + i];
    }
  }
  // bf scatter (Cin=3): lanes 0..23 -> c=lane/3, i=lane%3
  int b0e = valid ? rowbf[dst] : 0, b1e = valid ? rowbf[dst+1] : 0;
  for (int e = b0e; e < b1e; ++e) {
    Geom gm = gbf[e];
    int src = bfsrc[e];
    if (lane < 24) {
      int c = lane / 3, i = lane - 3*c;
      int dx = c & 1, dy = (c >> 1) & 1, dz = c >> 2;
      float w = gm.win * (dx ? gm.fx : 1.0f - gm.fx)
                       * (dy ? gm.fy : 1.0f - gm.fy)
                       * (dz ? gm.fz : 1.0f - gm.fz);
      int bin = gm.base + dz*16 + dy*4 + dx;
      To[g][bin*3 + i] += w * bfeats[src*3 + i];
    }
  }
  __syncthreads();
  if (!valid) return;
  if (lane < 32) {
    int o = lane;
    float acc = 0.0f;
    #pragma unroll 4
    for (int bi = 0; bi < 256; ++bi) acc += Tf[g][bi] * W0f[bi*32 + o];
    float d0 = bd0[o];
    #pragma unroll
    for (int i = 0; i < 4; ++i) d0 += fd[g][i] * Wd0[i*32 + o];
    x0[dst*96 + 32 + o] = fmaxf(acc + b0f[o], 0.0f);
    x0[dst*96 + 64 + o] = fmaxf(d0, 0.0f);
  } else {
    int o = lane - 32;
    float acc = 0.0f;
    #pragma unroll 4
    for (int bi = 0; bi < 192; ++bi) acc += To[g][bi] * W0o[bi*32 + o];
    x0[dst*96 + o] = fmaxf(acc + b0o[o], 0.0f);
  }
}

// ---------------- generic cconv layer, COUT=64 ----------------
// G dsts per block, 2 waves per dst (scatter uses LDS atomics), split-K GEMM.
template<int CIN, int G>
__global__ __launch_bounds__(G*128) void k_cconv(const float* __restrict__ xin,
                                                 const int* __restrict__ esrc,
                                                 const int* __restrict__ rowp,
                                                 const Geom* __restrict__ geo,
                                                 const float* __restrict__ Wc, const float* __restrict__ bc,
                                                 const float* __restrict__ Wd, const float* __restrict__ bd,
                                                 const float* __restrict__ hres,  // residual (may be null)
                                                 float* __restrict__ hout,        // pre-relu (may be null)
                                                 float* __restrict__ xout,        // relu out
                                                 int n) {
  constexpr int NT = G * 128;
  constexpr int KTOT = 64 * CIN;
  constexpr int KCH = KTOT / 2;
  __shared__ float T[G][KTOT];
  __shared__ float xdsh[G][CIN];
  __shared__ float red[G*64];
  int tid = threadIdx.x;
  for (int idx = tid; idx < G*KTOT; idx += NT) ((float*)T)[idx] = 0.0f;
  for (int idx = tid; idx < G*CIN; idx += NT) {
    int g = idx / CIN, i = idx - g*CIN;
    int dst = blockIdx.x * G + g;
    xdsh[g][i] = (dst < n) ? xin[dst*CIN + i] : 0.0f;
  }
  __syncthreads();
  // scatter: wave -> (dst g, sub-half of edges)
  {
    int wave = tid >> 6, lane = tid & 63;
    int g = wave >> 1, sub = wave & 1;
    int dst = blockIdx.x * G + g;
    int e0 = 0, e1 = 0;
    if (dst < n) { e0 = rowp[dst]; e1 = rowp[dst+1]; }
    for (int e = e0 + sub; e < e1; e += 2) {
      Geom gm = geo[e];
      int src = esrc[e];
      float f0 = xin[src*CIN + lane];
      float f1 = 0.0f;
      if constexpr (CIN > 64) { if (lane < CIN-64) f1 = xin[src*CIN + 64 + lane]; }
      #pragma unroll
      for (int c = 0; c < 8; ++c) {
        int dx = c & 1, dy = (c >> 1) & 1, dz = c >> 2;
        float w = gm.win * (dx ? gm.fx : 1.0f - gm.fx)
                         * (dy ? gm.fy : 1.0f - gm.fy)
                         * (dz ? gm.fz : 1.0f - gm.fz);
        int bin = gm.base + dz*16 + dy*4 + dx;
        atomicAdd(&T[g][bin*CIN + lane], w * f0);
        if constexpr (CIN > 64) { if (lane < CIN-64) atomicAdd(&T[g][bin*CIN + 64 + lane], w * f1); }
      }
    }
  }
  __syncthreads();
  // GEMM: o = tid&63, slot=tid>>6: g=slot/2, k=slot&1 (split-K halves)
  int o = tid & 63, slot = tid >> 6;
  int g = slot >> 1, k = slot & 1;
  int dst = blockIdx.x * G + g;
  float acc0 = 0.0f, acc1 = 0.0f;
  {
    const float4* Tp4 = (const float4*)(&T[g][k*KCH]);
    const float*  Wp  = Wc + (size_t)(k*KCH)*64 + o;
    #pragma unroll 4
    for (int q = 0; q < KCH/4; ++q) {
      float4 tv = Tp4[q];
      const float* wq = Wp + (size_t)q*256;
      acc0 += tv.x * wq[0]   + tv.y * wq[64];
      acc1 += tv.z * wq[128] + tv.w * wq[192];
    }
  }
  float acc = acc0 + acc1;
  if (k == 1) red[g*64 + o] = acc;
  __syncthreads();
  if (k == 0 && dst < n) {
    acc += red[g*64 + o];
    float accd = bc[o] + bd[o];
    #pragma unroll 8
    for (int i = 0; i < CIN; ++i) accd += xdsh[g][i] * Wd[i*64 + o];
    float h = acc + accd;
    if (hres) h += hres[(size_t)dst*64 + o];
    if (hout) hout[(size_t)dst*64 + o] = h;
    xout[(size_t)dst*64 + o] = fmaxf(h, 0.0f);
  }
}

// ---------------- layer3: CIN=64, COUT=3 + final update ----------------
__global__ __launch_bounds__(256) void k_layer3(const float* __restrict__ xin,
                                                const int* __restrict__ esrc,
                                                const int* __restrict__ rowp,
                                                const Geom* __restrict__ geo,
                                                const float* __restrict__ Wc, const float* __restrict__ bc,
                                                const float* __restrict__ Wd, const float* __restrict__ bd,
                                                const float* __restrict__ pos,
                                                const float* __restrict__ pos2,
                                                float* __restrict__ out, int n) {
  constexpr int CIN = 64;
  __shared__ float T[2][64*CIN];
  __shared__ float xdsh[2][CIN];
  __shared__ float red[2][4];
  int tid = threadIdx.x;
  for (int idx = tid; idx < 2*64*CIN; idx += 256) ((float*)T)[idx] = 0.0f;
  for (int idx = tid; idx < 2*CIN; idx += 256) {
    int g = idx / CIN, i = idx - g*CIN;
    int dst = blockIdx.x * 2 + g;
    xdsh[g][i] = (dst < n) ? xin[dst*CIN + i] : 0.0f;
  }
  if (tid < 8) ((float*)red)[tid] = 0.0f;
  __syncthreads();
  {
    int wave = tid >> 6, lane = tid & 63;
    int g = wave >> 1, sub = wave & 1;
    int dst = blockIdx.x * 2 + g;
    int e0 = 0, e1 = 0;
    if (dst < n) { e0 = rowp[dst]; e1 = rowp[dst+1]; }
    for (int e = e0 + sub; e < e1; e += 2) {
      Geom gm = geo[e];
      int src = esrc[e];
      float f0 = xin[src*CIN + lane];
      #pragma unroll
      for (int c = 0; c < 8; ++c) {
        int dx = c & 1, dy = (c >> 1) & 1, dz = c >> 2;
        float w = gm.win * (dx ? gm.fx : 1.0f - gm.fx)
                         * (dy ? gm.fy : 1.0f - gm.fy)
                         * (dz ? gm.fz : 1.0f - gm.fz);
        int bin = gm.base + dz*16 + dy*4 + dx;
        atomicAdd(&T[g][bin*CIN + lane], w * f0);
      }
    }
  }
  __syncthreads();
  // GEMM: per dst 128 threads: o=t2&3 (o<3 active), kk=t2>>2 covers 128 of 4096
  int g = tid >> 7, t2 = tid & 127, o = t2 & 3, kk = t2 >> 2;
  if (o < 3) {
    float acc = 0.0f;
    const float4* Tp4 = (const float4*)(&T[g][kk*128]);
    const float*  Wp  = Wc + (size_t)(kk*128)*3 + o;
    #pragma unroll 4
    for (int q = 0; q < 32; ++q) {
      float4 tv = Tp4[q];
      const float* wq = Wp + q*12;
      acc += tv.x * wq[0] + tv.y * wq[3] + tv.z * wq[6] + tv.w * wq[9];
    }
    atomicAdd(&red[g][o], acc);
  }
  __syncthreads();
  int dst = blockIdx.x * 2 + g;
  if (o < 3 && kk == 0 && dst < n) {
    float h3 = red[g][o] + bc[o] + bd[o];
    #pragma unroll 8
    for (int i = 0; i < CIN; ++i) h3 += xdsh[g][i] * Wd[i*3 + o];
    float pn = pos2[dst*3 + o] + h3 * (1.0f / 128.0f);
    float vn = (pn - pos[dst*3 + o]) * (1.0f / DT);
    out[(size_t)dst*6 + o] = pn;
    out[(size_t)dst*6 + 3 + o] = vn;
  }
}

// ---------------- host ----------------
extern "C" void kernel_launch(void* const* d_in, const int* in_sizes, int n_in,
                              void* d_out, int out_size, void* d_ws, size_t ws_size,
                              hipStream_t stream) {
  const float* pos    = (const float*)d_in[0];
  const float* vel    = (const float*)d_in[1];
  const float* box    = (const float*)d_in[2];
  const float* bfeats = (const float*)d_in[3];
  const int*   ffsrc  = (const int*)d_in[4];
  const int*   ffdst  = (const int*)d_in[5];
  const int*   bfsrc  = (const int*)d_in[6];
  const int*   bfdst  = (const int*)d_in[7];
  const float* W0f = (const float*)d_in[8];
  const float* b0f = (const float*)d_in[9];
  const float* W0o = (const float*)d_in[10];
  const float* b0o = (const float*)d_in[11];
  const float* Wd0 = (const float*)d_in[12];
  const float* bd0 = (const float*)d_in[13];
  const float* Wc1 = (const float*)d_in[14];
  const float* bc1 = (const float*)d_in[15];
  const float* Wd1 = (const float*)d_in[16];
  const float* bd1 = (const float*)d_in[17];
  const float* Wc2 = (const float*)d_in[18];
  const float* bc2 = (const float*)d_in[19];
  const float* Wd2 = (const float*)d_in[20];
  const float* bd2 = (const float*)d_in[21];
  const float* Wc3 = (const float*)d_in[22];
  const float* bc3 = (const float*)d_in[23];
  const float* Wd3 = (const float*)d_in[24];
  const float* bd3 = (const float*)d_in[25];

  int n   = in_sizes[0] / 3;
  int Eff = in_sizes[4];
  int Ebf = in_sizes[6];
  float* out = (float*)d_out;

  char* w = (char*)d_ws;
  auto alloc = [&](size_t bytes) -> char* {
    char* p = w; w += (bytes + 255) & ~size_t(255); return p;
  };
  float* pos2  = (float*)alloc((size_t)n*3*4);
  float* feats = (float*)alloc((size_t)n*4*4);
  float* x0    = (float*)alloc((size_t)n*96*4);
  float* h1    = (float*)alloc((size_t)n*64*4);
  float* x1    = (float*)alloc((size_t)n*64*4);
  float* x2    = (float*)alloc((size_t)n*64*4);
  int*   rowff = (int*)alloc((size_t)(n+1)*4);
  int*   rowbf = (int*)alloc((size_t)(n+1)*4);
  Geom*  gff   = (Geom*)alloc((size_t)Eff*sizeof(Geom));
  Geom*  gbf   = (Geom*)alloc((size_t)Ebf*sizeof(Geom));

  k_prep<<<(n+255)/256, 256, 0, stream>>>(pos, vel, pos2, feats, n);
  k_rowptr<<<(n+256)/256, 256, 0, stream>>>(ffdst, Eff, bfdst, Ebf, rowff, rowbf, n);
  k_geom<<<(Eff+255)/256, 256, 0, stream>>>(ffsrc, ffdst, pos2, pos2, gff, Eff);
  k_geom<<<(Ebf+255)/256, 256, 0, stream>>>(bfsrc, bfdst, box,  pos2, gbf, Ebf);
  k_layer0<<<(n+3)/4, 256, 0, stream>>>(feats, bfeats, ffsrc, rowff, gff,
                                        bfsrc, rowbf, gbf,
                                        W0f, b0f, W0o, b0o, Wd0, bd0, x0, n);
  k_cconv<96,2><<<(n+1)/2, 256, 0, stream>>>(x0, ffsrc, rowff, gff,
                                             Wc1, bc1, Wd1, bd1,
                                             nullptr, h1, x1, n);
  k_cconv<64,3><<<(n+2)/3, 384, 0, stream>>>(x1, ffsrc, rowff, gff,
                                             Wc2, bc2, Wd2, bd2,
                                             h1, nullptr, x2, n);
  k_layer3<<<(n+1)/2, 256, 0, stream>>>(x2, ffsrc, rowff, gff,
                                        Wc3, bc3, Wd3, bd3,
                                        pos, pos2, out, n);
}

// Round 2
// 7564.824 us; speedup vs baseline: 1.0029x; 1.0029x over previous
//
#include <hip/hip_runtime.h>
#include <math.h>

// ---------------- constants ----------------
constexpr float RADIUS     = 0.1125f;          // 1.5*6*0.025*0.5
constexpr float INV_RADIUS = 1.0f / RADIUS;
constexpr float DT         = 1.0f / 50.0f;
constexpr float FOPI       = 1.2732395447351628f; // 4/pi

struct Geom { float fx, fy, fz, win; int base; }; // 20 B

// ---------------- prep: pos2, feats=[1,vel2] ----------------
__global__ __launch_bounds__(256) void k_prep(const float* __restrict__ pos,
                                              const float* __restrict__ vel,
                                              float* __restrict__ pos2,
                                              float* __restrict__ feats, int n) {
  int i = blockIdx.x * blockDim.x + threadIdx.x;
  if (i >= n) return;
  float vx = vel[i*3+0], vy = vel[i*3+1], vz = vel[i*3+2];
  float v2x = vx, v2y = vy + DT * (-9.81f), v2z = vz;
  pos2[i*3+0] = pos[i*3+0] + DT * 0.5f * (v2x + vx);
  pos2[i*3+1] = pos[i*3+1] + DT * 0.5f * (v2y + vy);
  pos2[i*3+2] = pos[i*3+2] + DT * 0.5f * (v2z + vz);
  feats[i*4+0] = 1.0f;
  feats[i*4+1] = v2x; feats[i*4+2] = v2y; feats[i*4+3] = v2z;
}

// ---------------- rowptr ----------------
__global__ __launch_bounds__(256) void k_rowptr(const int* __restrict__ ffdst, int Eff,
                                                const int* __restrict__ bfdst, int Ebf,
                                                int* __restrict__ rowff, int* __restrict__ rowbf,
                                                int n) {
  int d = blockIdx.x * blockDim.x + threadIdx.x;
  if (d > n) return;
  { int lo = 0, hi = Eff;
    while (lo < hi) { int mid = (lo + hi) >> 1; if (ffdst[mid] < d) lo = mid + 1; else hi = mid; }
    rowff[d] = lo; }
  { int lo = 0, hi = Ebf;
    while (lo < hi) { int mid = (lo + hi) >> 1; if (bfdst[mid] < d) lo = mid + 1; else hi = mid; }
    rowbf[d] = lo; }
}

// ---------------- per-edge geometry ----------------
__global__ __launch_bounds__(256) void k_geom(const int* __restrict__ srcs,
                                              const int* __restrict__ dsts,
                                              const float* __restrict__ srcpos,
                                              const float* __restrict__ dstpos,
                                              Geom* __restrict__ geo, int E) {
  int e = blockIdx.x * blockDim.x + threadIdx.x;
  if (e >= E) return;
  int s = srcs[e], d = dsts[e];
  float rx = (srcpos[s*3+0] - dstpos[d*3+0]) * INV_RADIUS;
  float ry = (srcpos[s*3+1] - dstpos[d*3+1]) * INV_RADIUS;
  float rz = (srcpos[s*3+2] - dstpos[d*3+2]) * INV_RADIUS;
  float r2 = rx*rx + ry*ry + rz*rz;
  float t = 1.0f - r2;
  float win = t * t * t;
  win = fminf(fmaxf(win, 0.0f), 1.0f);
  float x = rx, y = ry, z = rz;
  float sq = r2;
  float norm = sqrtf(sq + 1e-24f);
  float xy_sq = x*x + y*y;
  bool zero = sq < 1e-12f;
  bool cone = 1.25f * z * z > xy_sq;
  float s_cone = sqrtf(3.0f * norm / (norm + fabsf(z) + 1e-12f));
  float s_side = norm / sqrtf(xy_sq + 1e-24f);
  float sgnz = (z > 0.0f) ? 1.0f : ((z < 0.0f) ? -1.0f : 0.0f);
  float xc = zero ? 0.0f : (cone ? x * s_cone : x * s_side);
  float yc = zero ? 0.0f : (cone ? y * s_cone : y * s_side);
  float zc = zero ? 0.0f : (cone ? sgnz * norm : 1.5f * z);
  float nxy_sq = xc*xc + yc*yc;
  float nxy = sqrtf(nxy_sq + 1e-24f);
  bool zero_xy = nxy_sq < 1e-12f;
  bool xbig = fabsf(xc) > fabsf(yc);
  float dx_ = (fabsf(xc) > 1e-12f) ? xc : 1.0f;
  float dy_ = (fabsf(yc) > 1e-12f) ? yc : 1.0f;
  float sgnx = (xc > 0.0f) ? 1.0f : ((xc < 0.0f) ? -1.0f : 0.0f);
  float sgny = (yc > 0.0f) ? 1.0f : ((yc < 0.0f) ? -1.0f : 0.0f);
  float tx = sgnx * nxy, ty = sgny * nxy;
  float xq = zero_xy ? 0.0f : (xbig ? tx : ty * FOPI * atanf(xc / dy_));
  float yq = zero_xy ? 0.0f : (xbig ? tx * FOPI * atanf(yc / dx_) : ty);
  float gx = (xq + 1.0f) * 1.5f;
  float gy = (yq + 1.0f) * 1.5f;
  float gz = (zc + 1.0f) * 1.5f;
  float g0x = fminf(fmaxf(floorf(gx), 0.0f), 2.0f);
  float g0y = fminf(fmaxf(floorf(gy), 0.0f), 2.0f);
  float g0z = fminf(fmaxf(floorf(gz), 0.0f), 2.0f);
  Geom g;
  g.fx = gx - g0x; g.fy = gy - g0y; g.fz = gz - g0z; g.win = win;
  g.base = (int)g0z * 16 + (int)g0y * 4 + (int)g0x;
  geo[e] = g;
}

// ---------------- layer0 ----------------
__global__ __launch_bounds__(256) void k_layer0(const float* __restrict__ feats,
                                                const float* __restrict__ bfeats,
                                                const int* __restrict__ ffsrc,
                                                const int* __restrict__ rowff,
                                                const Geom* __restrict__ gff,
                                                const int* __restrict__ bfsrc,
                                                const int* __restrict__ rowbf,
                                                const Geom* __restrict__ gbf,
                                                const float* __restrict__ W0f, const float* __restrict__ b0f,
                                                const float* __restrict__ W0o, const float* __restrict__ b0o,
                                                const float* __restrict__ Wd0, const float* __restrict__ bd0,
                                                float* __restrict__ x0, int n) {
  __shared__ float Tf[4][64*4];
  __shared__ float To[4][64*3];
  __shared__ float fd[4][4];
  int tid = threadIdx.x, lane = tid & 63, g = tid >> 6;
  int dst = blockIdx.x * 4 + g;
  bool valid = dst < n;
  for (int idx = lane; idx < 64*4; idx += 64) Tf[g][idx] = 0.0f;
  for (int idx = lane; idx < 64*3; idx += 64) To[g][idx] = 0.0f;
  if (lane < 4) fd[g][lane] = valid ? feats[dst*4 + lane] : 0.0f;
  __syncthreads();
  // ---- ff scatter (Cin=4), depth-2 pipeline ----
  {
    int e0 = valid ? rowff[dst] : 0, e1 = valid ? rowff[dst+1] : 0;
    int i4 = lane & 3;
    int eA = e0, eB = e0 + 1;
    Geom gA, gB; float fA = 0.0f, fB = 0.0f;
    if (eA < e1) { gA = gff[eA]; fA = feats[ffsrc[eA]*4 + i4]; }
    if (eB < e1) { gB = gff[eB]; fB = feats[ffsrc[eB]*4 + i4]; }
    while (eA < e1) {
      int eC = eA + 2;
      Geom gC; float fC = 0.0f;
      if (eC < e1) { gC = gff[eC]; fC = feats[ffsrc[eC]*4 + i4]; }
      if (lane < 32) {
        int c = lane >> 2;
        int dx = c & 1, dy = (c >> 1) & 1, dz = c >> 2;
        float w = gA.win * (dx ? gA.fx : 1.0f - gA.fx)
                         * (dy ? gA.fy : 1.0f - gA.fy)
                         * (dz ? gA.fz : 1.0f - gA.fz);
        int bin = gA.base + dz*16 + dy*4 + dx;
        Tf[g][bin*4 + i4] += w * fA;
      }
      gA = gB; fA = fB; gB = gC; fB = fC;
      eA = eB; eB = eC;
    }
  }
  // ---- bf scatter (Cin=3), depth-2 pipeline ----
  {
    int e0 = valid ? rowbf[dst] : 0, e1 = valid ? rowbf[dst+1] : 0;
    int c3 = lane / 3, i3 = lane - 3*c3;
    int i3c = (lane < 24) ? i3 : 0;
    int eA = e0, eB = e0 + 1;
    Geom gA, gB; float fA = 0.0f, fB = 0.0f;
    if (eA < e1) { gA = gbf[eA]; fA = bfeats[bfsrc[eA]*3 + i3c]; }
    if (eB < e1) { gB = gbf[eB]; fB = bfeats[bfsrc[eB]*3 + i3c]; }
    while (eA < e1) {
      int eC = eA + 2;
      Geom gC; float fC = 0.0f;
      if (eC < e1) { gC = gbf[eC]; fC = bfeats[bfsrc[eC]*3 + i3c]; }
      if (lane < 24) {
        int dx = c3 & 1, dy = (c3 >> 1) & 1, dz = c3 >> 2;
        float w = gA.win * (dx ? gA.fx : 1.0f - gA.fx)
                         * (dy ? gA.fy : 1.0f - gA.fy)
                         * (dz ? gA.fz : 1.0f - gA.fz);
        int bin = gA.base + dz*16 + dy*4 + dx;
        To[g][bin*3 + i3] += w * fA;
      }
      gA = gB; fA = fB; gB = gC; fB = fC;
      eA = eB; eB = eC;
    }
  }
  __syncthreads();
  if (!valid) return;
  if (lane < 32) {
    int o = lane;
    float acc = 0.0f;
    #pragma unroll 4
    for (int bi = 0; bi < 256; ++bi) acc += Tf[g][bi] * W0f[bi*32 + o];
    float d0 = bd0[o];
    #pragma unroll
    for (int i = 0; i < 4; ++i) d0 += fd[g][i] * Wd0[i*32 + o];
    x0[dst*96 + 32 + o] = fmaxf(acc + b0f[o], 0.0f);
    x0[dst*96 + 64 + o] = fmaxf(d0, 0.0f);
  } else {
    int o = lane - 32;
    float acc = 0.0f;
    #pragma unroll 4
    for (int bi = 0; bi < 192; ++bi) acc += To[g][bi] * W0o[bi*32 + o];
    x0[dst*96 + o] = fmaxf(acc + b0o[o], 0.0f);
  }
}

// ---------------- generic cconv layer, COUT=64 ----------------
template<int CIN, int G>
__global__ __launch_bounds__(G*128) void k_cconv(const float* __restrict__ xin,
                                                 const int* __restrict__ esrc,
                                                 const int* __restrict__ rowp,
                                                 const Geom* __restrict__ geo,
                                                 const float* __restrict__ Wc, const float* __restrict__ bc,
                                                 const float* __restrict__ Wd, const float* __restrict__ bd,
                                                 const float* __restrict__ hres,
                                                 float* __restrict__ hout,
                                                 float* __restrict__ xout,
                                                 int n) {
  constexpr int NT = G * 128;
  constexpr int KTOT = 64 * CIN;
  constexpr int KCH = KTOT / 2;
  __shared__ float T[G][KTOT];
  __shared__ float xdsh[G][CIN];
  __shared__ float red[G*64];
  int tid = threadIdx.x;
  for (int idx = tid; idx < G*KTOT; idx += NT) ((float*)T)[idx] = 0.0f;
  for (int idx = tid; idx < G*CIN; idx += NT) {
    int g = idx / CIN, i = idx - g*CIN;
    int dst = blockIdx.x * G + g;
    xdsh[g][i] = (dst < n) ? xin[dst*CIN + i] : 0.0f;
  }
  __syncthreads();
  // ---- scatter: depth-2 pipelined ----
  {
    int wave = tid >> 6, lane = tid & 63;
    int g = wave >> 1, sub = wave & 1;
    int dst = blockIdx.x * G + g;
    int e0 = 0, e1 = 0;
    if (dst < n) { e0 = rowp[dst]; e1 = rowp[dst+1]; }
    int eA = e0 + sub, eB = eA + 2;
    Geom gA, gB; float fA0 = 0, fA1 = 0, fB0 = 0, fB1 = 0;
    if (eA < e1) {
      gA = geo[eA]; int s = esrc[eA];
      fA0 = xin[s*CIN + lane];
      if constexpr (CIN > 64) { if (lane < CIN-64) fA1 = xin[s*CIN + 64 + lane]; }
    }
    if (eB < e1) {
      gB = geo[eB]; int s = esrc[eB];
      fB0 = xin[s*CIN + lane];
      if constexpr (CIN > 64) { if (lane < CIN-64) fB1 = xin[s*CIN + 64 + lane]; }
    }
    while (eA < e1) {
      int eC = eA + 4;
      Geom gC; float fC0 = 0, fC1 = 0;
      if (eC < e1) {
        gC = geo[eC]; int s = esrc[eC];
        fC0 = xin[s*CIN + lane];
        if constexpr (CIN > 64) { if (lane < CIN-64) fC1 = xin[s*CIN + 64 + lane]; }
      }
      #pragma unroll
      for (int c = 0; c < 8; ++c) {
        int dx = c & 1, dy = (c >> 1) & 1, dz = c >> 2;
        float w = gA.win * (dx ? gA.fx : 1.0f - gA.fx)
                         * (dy ? gA.fy : 1.0f - gA.fy)
                         * (dz ? gA.fz : 1.0f - gA.fz);
        int bin = gA.base + dz*16 + dy*4 + dx;
        atomicAdd(&T[g][bin*CIN + lane], w * fA0);
        if constexpr (CIN > 64) { if (lane < CIN-64) atomicAdd(&T[g][bin*CIN + 64 + lane], w * fA1); }
      }
      gA = gB; fA0 = fB0; fA1 = fB1;
      gB = gC; fB0 = fC0; fB1 = fC1;
      eA = eB; eB = eC;
    }
  }
  __syncthreads();
  // ---- GEMM: T-broadcast reads (conflict-free), coalesced W ----
  int o = tid & 63, slot = tid >> 6;
  int g = slot >> 1, k = slot & 1;
  int dst = blockIdx.x * G + g;
  float acc0 = 0.0f, acc1 = 0.0f;
  {
    const float4* Tp4 = (const float4*)(&T[g][k*KCH]);
    const float*  Wp  = Wc + (size_t)(k*KCH)*64 + o;
    #pragma unroll 4
    for (int q = 0; q < KCH/4; ++q) {
      float4 tv = Tp4[q];
      const float* wq = Wp + (size_t)q*256;
      acc0 += tv.x * wq[0]   + tv.y * wq[64];
      acc1 += tv.z * wq[128] + tv.w * wq[192];
    }
  }
  float acc = acc0 + acc1;
  if (k == 1) red[g*64 + o] = acc;
  __syncthreads();
  if (k == 0 && dst < n) {
    acc += red[g*64 + o];
    float accd = bc[o] + bd[o];
    #pragma unroll 8
    for (int i = 0; i < CIN; ++i) accd += xdsh[g][i] * Wd[i*64 + o];
    float h = acc + accd;
    if (hres) h += hres[(size_t)dst*64 + o];
    if (hout) hout[(size_t)dst*64 + o] = h;
    xout[(size_t)dst*64 + o] = fmaxf(h, 0.0f);
  }
}

// ---------------- layer3: CIN=64, COUT=3 + final update ----------------
__global__ __launch_bounds__(256) void k_layer3(const float* __restrict__ xin,
                                                const int* __restrict__ esrc,
                                                const int* __restrict__ rowp,
                                                const Geom* __restrict__ geo,
                                                const float* __restrict__ Wc, const float* __restrict__ bc,
                                                const float* __restrict__ Wd, const float* __restrict__ bd,
                                                const float* __restrict__ pos,
                                                const float* __restrict__ pos2,
                                                float* __restrict__ out, int n) {
  constexpr int CIN = 64;
  __shared__ float T[2][64*CIN];
  __shared__ float xdsh[2][CIN];
  __shared__ float red[2][4];
  int tid = threadIdx.x;
  for (int idx = tid; idx < 2*64*CIN; idx += 256) ((float*)T)[idx] = 0.0f;
  for (int idx = tid; idx < 2*CIN; idx += 256) {
    int g = idx / CIN, i = idx - g*CIN;
    int dst = blockIdx.x * 2 + g;
    xdsh[g][i] = (dst < n) ? xin[dst*CIN + i] : 0.0f;
  }
  if (tid < 8) ((float*)red)[tid] = 0.0f;
  __syncthreads();
  // ---- scatter, depth-2 pipelined ----
  {
    int wave = tid >> 6, lane = tid & 63;
    int g = wave >> 1, sub = wave & 1;
    int dst = blockIdx.x * 2 + g;
    int e0 = 0, e1 = 0;
    if (dst < n) { e0 = rowp[dst]; e1 = rowp[dst+1]; }
    int eA = e0 + sub, eB = eA + 2;
    Geom gA, gB; float fA0 = 0, fB0 = 0;
    if (eA < e1) { gA = geo[eA]; fA0 = xin[esrc[eA]*CIN + lane]; }
    if (eB < e1) { gB = geo[eB]; fB0 = xin[esrc[eB]*CIN + lane]; }
    while (eA < e1) {
      int eC = eA + 4;
      Geom gC; float fC0 = 0;
      if (eC < e1) { gC = geo[eC]; fC0 = xin[esrc[eC]*CIN + lane]; }
      #pragma unroll
      for (int c = 0; c < 8; ++c) {
        int dx = c & 1, dy = (c >> 1) & 1, dz = c >> 2;
        float w = gA.win * (dx ? gA.fx : 1.0f - gA.fx)
                         * (dy ? gA.fy : 1.0f - gA.fy)
                         * (dz ? gA.fz : 1.0f - gA.fz);
        int bin = gA.base + dz*16 + dy*4 + dx;
        atomicAdd(&T[g][bin*CIN + lane], w * fA0);
      }
      gA = gB; fA0 = fB0; gB = gC; fB0 = fC0;
      eA = eB; eB = eC;
    }
  }
  __syncthreads();
  // ---- GEMM: conflict-free T reads, vectorized coalesced W, shuffle reduce ----
  {
    int lane = tid & 63, wave = tid >> 6;
    int g = wave >> 1, h = wave & 1;
    float a0 = 0, a1 = 0, a2 = 0;
    const float* Tg = T[g];
    for (int k0 = h*2048; k0 < h*2048 + 2048; k0 += 256) {
      int k = k0 + lane*4;
      float4 tv = *(const float4*)&Tg[k];
      const float4* wr4 = (const float4*)(Wc + (size_t)k*3);
      float4 w0 = wr4[0], w1 = wr4[1], w2 = wr4[2];
      a0 += tv.x*w0.x + tv.y*w0.w + tv.z*w1.z + tv.w*w2.y;
      a1 += tv.x*w0.y + tv.y*w1.x + tv.z*w1.w + tv.w*w2.z;
      a2 += tv.x*w0.z + tv.y*w1.y + tv.z*w2.x + tv.w*w2.w;
    }
    #pragma unroll
    for (int off = 32; off > 0; off >>= 1) {
      a0 += __shfl_down(a0, off, 64);
      a1 += __shfl_down(a1, off, 64);
      a2 += __shfl_down(a2, off, 64);
    }
    if (lane == 0) {
      atomicAdd(&red[g][0], a0);
      atomicAdd(&red[g][1], a1);
      atomicAdd(&red[g][2], a2);
    }
  }
  __syncthreads();
  if (tid < 6) {
    int g2 = tid / 3, o = tid - 3*g2;
    int dst = blockIdx.x * 2 + g2;
    if (dst < n) {
      float h3 = red[g2][o] + bc[o] + bd[o];
      #pragma unroll 8
      for (int i = 0; i < CIN; ++i) h3 += xdsh[g2][i] * Wd[i*3 + o];
      float pn = pos2[dst*3 + o] + h3 * (1.0f / 128.0f);
      float vn = (pn - pos[dst*3 + o]) * (1.0f / DT);
      out[(size_t)dst*6 + o] = pn;
      out[(size_t)dst*6 + 3 + o] = vn;
    }
  }
}

// ---------------- host ----------------
extern "C" void kernel_launch(void* const* d_in, const int* in_sizes, int n_in,
                              void* d_out, int out_size, void* d_ws, size_t ws_size,
                              hipStream_t stream) {
  const float* pos    = (const float*)d_in[0];
  const float* vel    = (const float*)d_in[1];
  const float* box    = (const float*)d_in[2];
  const float* bfeats = (const float*)d_in[3];
  const int*   ffsrc  = (const int*)d_in[4];
  const int*   ffdst  = (const int*)d_in[5];
  const int*   bfsrc  = (const int*)d_in[6];
  const int*   bfdst  = (const int*)d_in[7];
  const float* W0f = (const float*)d_in[8];
  const float* b0f = (const float*)d_in[9];
  const float* W0o = (const float*)d_in[10];
  const float* b0o = (const float*)d_in[11];
  const float* Wd0 = (const float*)d_in[12];
  const float* bd0 = (const float*)d_in[13];
  const float* Wc1 = (const float*)d_in[14];
  const float* bc1 = (const float*)d_in[15];
  const float* Wd1 = (const float*)d_in[16];
  const float* bd1 = (const float*)d_in[17];
  const float* Wc2 = (const float*)d_in[18];
  const float* bc2 = (const float*)d_in[19];
  const float* Wd2 = (const float*)d_in[20];
  const float* bd2 = (const float*)d_in[21];
  const float* Wc3 = (const float*)d_in[22];
  const float* bc3 = (const float*)d_in[23];
  const float* Wd3 = (const float*)d_in[24];
  const float* bd3 = (const float*)d_in[25];

  int n   = in_sizes[0] / 3;
  int Eff = in_sizes[4];
  int Ebf = in_sizes[6];
  float* out = (float*)d_out;

  char* w = (char*)d_ws;
  auto alloc = [&](size_t bytes) -> char* {
    char* p = w; w += (bytes + 255) & ~size_t(255); return p;
  };
  float* pos2  = (float*)alloc((size_t)n*3*4);
  float* feats = (float*)alloc((size_t)n*4*4);
  float* x0    = (float*)alloc((size_t)n*96*4);
  float* h1    = (float*)alloc((size_t)n*64*4);
  float* x1    = (float*)alloc((size_t)n*64*4);
  float* x2    = (float*)alloc((size_t)n*64*4);
  int*   rowff = (int*)alloc((size_t)(n+1)*4);
  int*   rowbf = (int*)alloc((size_t)(n+1)*4);
  Geom*  gff   = (Geom*)alloc((size_t)Eff*sizeof(Geom));
  Geom*  gbf   = (Geom*)alloc((size_t)Ebf*sizeof(Geom));

  k_prep<<<(n+255)/256, 256, 0, stream>>>(pos, vel, pos2, feats, n);
  k_rowptr<<<(n+256)/256, 256, 0, stream>>>(ffdst, Eff, bfdst, Ebf, rowff, rowbf, n);
  k_geom<<<(Eff+255)/256, 256, 0, stream>>>(ffsrc, ffdst, pos2, pos2, gff, Eff);
  k_geom<<<(Ebf+255)/256, 256, 0, stream>>>(bfsrc, bfdst, box,  pos2, gbf, Ebf);
  k_layer0<<<(n+3)/4, 256, 0, stream>>>(feats, bfeats, ffsrc, rowff, gff,
                                        bfsrc, rowbf, gbf,
                                        W0f, b0f, W0o, b0o, Wd0, bd0, x0, n);
  k_cconv<96,2><<<(n+1)/2, 256, 0, stream>>>(x0, ffsrc, rowff, gff,
                                             Wc1, bc1, Wd1, bd1,
                                             nullptr, h1, x1, n);
  k_cconv<64,3><<<(n+2)/3, 384, 0, stream>>>(x1, ffsrc, rowff, gff,
                                             Wc2, bc2, Wd2, bd2,
                                             h1, nullptr, x2, n);
  k_layer3<<<(n+1)/2, 256, 0, stream>>>(x2, ffsrc, rowff, gff,
                                        Wc3, bc3, Wd3, bd3,
                                        pos, pos2, out, n);
}